// Round 2
// baseline (334.614 us; speedup 1.0000x reference)
//
#include <hip/hip_runtime.h>
#include <math.h>

#define EPSV 1e-8f

constexpr int D  = 1024;
constexpr int E  = 64;
constexpr int TB = 32;    // tokens per block
constexpr int TW = 8;     // tokens per wave

// ---------- fallback: expert inverse norms only ----------
__global__ __launch_bounds__(256) void expert_norm_kernel(const float* __restrict__ expw,
                                                          float* __restrict__ einv) {
  const int b = blockIdx.x;
  const int tid = threadIdx.x;
  const float4 v = *reinterpret_cast<const float4*>(expw + (size_t)b * D + tid * 4);
  float ss = v.x * v.x + v.y * v.y + v.z * v.z + v.w * v.w;
#pragma unroll
  for (int m = 32; m >= 1; m >>= 1) ss += __shfl_xor(ss, m);
  __shared__ float red[4];
  if ((tid & 63) == 0) red[tid >> 6] = ss;
  __syncthreads();
  if (tid == 0) {
    float t = (red[0] + red[1]) + (red[2] + red[3]);
    einv[b] = 1.0f / (sqrtf(t) + EPSV);
  }
}

// ---------- prep: expert inverse norms + transpose to expT4[d4][e] ----------
__global__ __launch_bounds__(256) void prep_kernel(const float* __restrict__ expw,
                                                   float* __restrict__ einv,
                                                   float4* __restrict__ expT4) {
  const int e = blockIdx.x;          // one expert per block
  const int d4 = threadIdx.x;        // 256 float4 chunks per row
  const float4 v = *reinterpret_cast<const float4*>(expw + (size_t)e * D + d4 * 4);
  expT4[d4 * E + e] = v;             // transposed layout
  float ss = v.x * v.x + v.y * v.y + v.z * v.z + v.w * v.w;
#pragma unroll
  for (int m = 32; m >= 1; m >>= 1) ss += __shfl_xor(ss, m);
  __shared__ float red[4];
  if ((threadIdx.x & 63) == 0) red[threadIdx.x >> 6] = ss;
  __syncthreads();
  if (threadIdx.x == 0) {
    float t = (red[0] + red[1]) + (red[2] + red[3]);
    einv[e] = 1.0f / (sqrtf(t) + EPSV);
  }
}

// ---------- main gating kernel (no LDS in hot loop) ----------
__global__ __launch_bounds__(256) void gate_kernel(const float* __restrict__ tok,
                                                   const float* __restrict__ expw,
                                                   const float* __restrict__ cache,
                                                   const float* __restrict__ einv_g,
                                                   const float4* __restrict__ expT4,
                                                   const int use_t,
                                                   float* __restrict__ out_idx,
                                                   float* __restrict__ out_w) {
  __shared__ float s_sq[TB][8];
  __shared__ float s_tinv[TB];

  const int tid = threadIdx.x;
  const int lane = tid & 63;
  const int wid = tid >> 6;
  const int bt = blockIdx.x * TB;

  const float einv = einv_g[lane];         // lane == expert id
  const float bonus = 0.1f * cache[lane];

  // ---------- phase A: token sumsq (distributed, coalesced; warms L2/L3) ----------
  {
    const int tr = tid >> 3, tp = tid & 7;   // 8 threads per token row
    float sq = 0.f;
    const float* trow = tok + (size_t)(bt + tr) * D + tp * 16;
#pragma unroll 1
    for (int c = 0; c < 8; ++c) {
      const float4* g = reinterpret_cast<const float4*>(trow + c * 128);
#pragma unroll
      for (int i = 0; i < 4; ++i) {
        const float4 a = g[i];
        sq += a.x * a.x + a.y * a.y + a.z * a.z + a.w * a.w;
      }
    }
    s_sq[tr][tp] = sq;
  }
  __syncthreads();
  if (tid < TB) {
    float ss = 0.f;
#pragma unroll
    for (int p = 0; p < 8; ++p) ss += s_sq[tid][p];
    s_tinv[tid] = 1.0f / (sqrtf(ss) + EPSV);
  }
  __syncthreads();

  // ---------- phase B: sims. expert frag coalesced; token values wave-uniform ----------
  float acc[TW][4];
#pragma unroll
  for (int t = 0; t < TW; ++t)
#pragma unroll
    for (int j = 0; j < 4; ++j) acc[t][j] = 0.f;

  // unified expert addressing: transposed (stride E) or raw row (stride 1)
  const float4* ebase = use_t ? (expT4 + lane)
                              : reinterpret_cast<const float4*>(expw + (size_t)lane * D);
  const int estride = use_t ? E : 1;
  const float* tbase = tok + (size_t)(bt + wid * TW) * D;

#pragma unroll 4
  for (int d4 = 0; d4 < D / 4; ++d4) {
    const float4 ev = ebase[(size_t)d4 * estride];
#pragma unroll
    for (int t = 0; t < TW; ++t) {
      const float4 tv = *reinterpret_cast<const float4*>(tbase + (size_t)t * D + d4 * 4);
      acc[t][0] = fmaf(tv.x, ev.x, acc[t][0]);
      acc[t][1] = fmaf(tv.y, ev.y, acc[t][1]);
      acc[t][2] = fmaf(tv.z, ev.z, acc[t][2]);
      acc[t][3] = fmaf(tv.w, ev.w, acc[t][3]);
    }
  }

  // ---------- per-token selection (lane == expert) ----------
#pragma unroll 1
  for (int t = 0; t < TW; ++t) {
    const int trow = wid * TW + t;
    const float sim = (acc[t][0] + acc[t][1]) + (acc[t][2] + acc[t][3]);
    const float tinv = s_tinv[trow];

    // top-7 by sim, descending, ties -> lowest expert index (matches lax.top_k)
    float v = sim;
    int vi = lane;
    float cv[7];
    int ci[7];
#pragma unroll
    for (int r = 0; r < 7; ++r) {
      float rv = v;
      int ri = vi;
#pragma unroll
      for (int m = 32; m >= 1; m >>= 1) {
        float ov = __shfl_xor(rv, m);
        int oi = __shfl_xor(ri, m);
        if (ov > rv || (ov == rv && oi < ri)) { rv = ov; ri = oi; }
      }
      cv[r] = rv; ci[r] = ri;
      if (vi == ri) v = -INFINITY;  // mask winner in its owner lane
    }

    // reversed order l=0..6  <->  rank 6-l ; total = cos + 0.1*cache
    float tot[7];
    int gi[7];
#pragma unroll
    for (int l = 0; l < 7; ++l) {
      const int ce = ci[6 - l];
      const float ei = __shfl(einv, ce);
      const float bo = __shfl(bonus, ce);
      tot[l] = cv[6 - l] * tinv * ei + bo;
      gi[l] = ce;
    }

    // top-2 of tot, ties -> lowest l (stable like lax.top_k)
    float bv = tot[0]; int bl = 0; int bgi = gi[0];
#pragma unroll
    for (int l = 1; l < 7; ++l)
      if (tot[l] > bv) { bv = tot[l]; bl = l; bgi = gi[l]; }
    float sv = -INFINITY; int sgi = 0;
#pragma unroll
    for (int l = 0; l < 7; ++l) {
      if (l == bl) continue;
      if (tot[l] > sv) { sv = tot[l]; sgi = gi[l]; }
    }

    // reference emits [second-best, best]; weights = softmax([sv, bv])
    const float e1 = expf(sv - bv);
    const float z = 1.0f + e1;
    if (lane == 0) {
      const int token = bt + trow;
      out_idx[2 * token]     = (float)sgi;
      out_idx[2 * token + 1] = (float)bgi;
      out_w[2 * token]     = e1 / z;
      out_w[2 * token + 1] = 1.0f / z;
    }
  }
}

extern "C" void kernel_launch(void* const* d_in, const int* in_sizes, int n_in,
                              void* d_out, int out_size, void* d_ws, size_t ws_size,
                              hipStream_t stream) {
  const float* tok   = (const float*)d_in[0];
  const float* expw  = (const float*)d_in[1];
  const float* cache = (const float*)d_in[2];
  float* out = (float*)d_out;

  float* einv = (float*)d_ws;                                   // 64 floats
  float4* expT4 = (float4*)((char*)d_ws + 1024);                // 256 KB, 16B-aligned
  const size_t need = 1024 + (size_t)(D / 4) * E * sizeof(float4);
  const int use_t = (ws_size >= need) ? 1 : 0;

  const int n_tok = in_sizes[0] / D;       // 32768
  const int n_out_idx = n_tok * 2;         // 65536

  if (use_t) {
    prep_kernel<<<E, 256, 0, stream>>>(expw, einv, expT4);
  } else {
    expert_norm_kernel<<<E, 256, 0, stream>>>(expw, einv);
  }
  gate_kernel<<<n_tok / TB, 256, 0, stream>>>(tok, expw, cache, einv, expT4, use_t,
                                              out, out + n_out_idx);
}

// Round 3
// 145.693 us; speedup vs baseline: 2.2967x; 2.2967x over previous
//
#include <hip/hip_runtime.h>
#include <math.h>

#define EPSV 1e-8f

constexpr int D   = 1024;
constexpr int E   = 64;
constexpr int TOK = 128;   // tokens per block
constexpr int DC  = 64;    // d-chunk (floats)
constexpr int NCH = D / DC;       // 16 chunks
constexpr int NS  = DC / 4;       // 16 float4 slots per row
constexpr int T   = 8;     // tokens per thread
constexpr int EX  = 4;     // experts per thread

// ---------- prep: expert inverse norms ----------
__global__ __launch_bounds__(256) void expert_norm_kernel(const float* __restrict__ expw,
                                                          float* __restrict__ einv) {
  const int b = blockIdx.x;
  const int tid = threadIdx.x;
  const float4 v = *reinterpret_cast<const float4*>(expw + (size_t)b * D + tid * 4);
  float ss = v.x * v.x + v.y * v.y + v.z * v.z + v.w * v.w;
#pragma unroll
  for (int m = 32; m >= 1; m >>= 1) ss += __shfl_xor(ss, m);
  __shared__ float red[4];
  if ((tid & 63) == 0) red[tid >> 6] = ss;
  __syncthreads();
  if (tid == 0) {
    float t = (red[0] + red[1]) + (red[2] + red[3]);
    einv[b] = 1.0f / (sqrtf(t) + EPSV);
  }
}

// ---------- main: register-tiled fp32 GEMM + fused double top-k ----------
__global__ __launch_bounds__(256) void gate_kernel(const float* __restrict__ tok,
                                                   const float* __restrict__ expw,
                                                   const float* __restrict__ cache,
                                                   const float* __restrict__ einv_g,
                                                   float* __restrict__ out_idx,
                                                   float* __restrict__ out_w) {
  __shared__ float4 s_tok4[TOK * NS];   // [row][slot], slot XOR-swizzled by (row>>3)&7
  __shared__ float4 s_exp4[E * NS];     // [row][slot], slot XOR-swizzled by (row>>2)&7
  __shared__ float  s_part[TOK][NS];    // token sumsq partials
  __shared__ float  s_tinv[TOK];
  __shared__ float  s_einv[E];
  __shared__ float  s_bonus[E];

  const int tid = threadIdx.x;
  const int ty = tid >> 4;      // 0..15  token group (8 tokens each)
  const int tx = tid & 15;      // 0..15  expert group (4 experts each)
  const int srow = tid >> 4;    // staging row-in-pass 0..15
  const int sslot = tid & 15;   // staging slot 0..15
  const int bt = blockIdx.x * TOK;

  if (tid < E) {
    s_einv[tid] = einv_g[tid];
    s_bonus[tid] = 0.1f * cache[tid];
  }

  float acc[T][EX];
#pragma unroll
  for (int k = 0; k < T; ++k)
#pragma unroll
    for (int j = 0; j < EX; ++j) acc[k][j] = 0.f;

  float sqp[8];
#pragma unroll
  for (int g = 0; g < 8; ++g) sqp[g] = 0.f;

  // prologue: load chunk 0
  float4 tg[8], eg[4];
#pragma unroll
  for (int g = 0; g < 8; ++g)
    tg[g] = *reinterpret_cast<const float4*>(tok + (size_t)(bt + srow + 16 * g) * D + sslot * 4);
#pragma unroll
  for (int h = 0; h < 4; ++h)
    eg[h] = *reinterpret_cast<const float4*>(expw + (size_t)(srow + 16 * h) * D + sslot * 4);

#pragma unroll 1
  for (int c = 0; c < NCH; ++c) {
    __syncthreads();  // previous compute done; LDS free
    // write staged regs -> LDS (swizzled), accumulate token sumsq
#pragma unroll
    for (int g = 0; g < 8; ++g) {
      const int row = srow + 16 * g;
      const int sl = sslot ^ ((row >> 3) & 7);
      s_tok4[row * NS + sl] = tg[g];
      sqp[g] += tg[g].x * tg[g].x + tg[g].y * tg[g].y + tg[g].z * tg[g].z + tg[g].w * tg[g].w;
    }
#pragma unroll
    for (int h = 0; h < 4; ++h) {
      const int row = srow + 16 * h;
      const int sl = sslot ^ ((row >> 2) & 7);
      s_exp4[row * NS + sl] = eg[h];
    }
    __syncthreads();
    // issue next chunk's loads (latency hides under compute)
    if (c + 1 < NCH) {
      const int off = (c + 1) * DC + sslot * 4;
#pragma unroll
      for (int g = 0; g < 8; ++g)
        tg[g] = *reinterpret_cast<const float4*>(tok + (size_t)(bt + srow + 16 * g) * D + off);
#pragma unroll
      for (int h = 0; h < 4; ++h)
        eg[h] = *reinterpret_cast<const float4*>(expw + (size_t)(srow + 16 * h) * D + off);
    }
    // compute chunk c
#pragma unroll
    for (int d4 = 0; d4 < NS; ++d4) {
      float4 ef[EX];
#pragma unroll
      for (int j = 0; j < EX; ++j)
        ef[j] = s_exp4[(tx * 4 + j) * NS + (d4 ^ (tx & 7))];
#pragma unroll
      for (int k = 0; k < T; ++k) {
        const float4 tv = s_tok4[(ty * 8 + k) * NS + (d4 ^ (ty & 7))];
#pragma unroll
        for (int j = 0; j < EX; ++j) {
          acc[k][j] = fmaf(tv.x, ef[j].x, acc[k][j]);
          acc[k][j] = fmaf(tv.y, ef[j].y, acc[k][j]);
          acc[k][j] = fmaf(tv.z, ef[j].z, acc[k][j]);
          acc[k][j] = fmaf(tv.w, ef[j].w, acc[k][j]);
        }
      }
    }
  }

  // token inverse norms
#pragma unroll
  for (int g = 0; g < 8; ++g) s_part[srow + 16 * g][sslot] = sqp[g];
  __syncthreads();
  if (tid < TOK) {
    float ss = 0.f;
#pragma unroll
    for (int p = 0; p < NS; ++p) ss += s_part[tid][p];
    s_tinv[tid] = 1.0f / (sqrtf(ss) + EPSV);
  }
  __syncthreads();

  // ---------- selection: 16-lane group (same ty) per token ----------
#pragma unroll 1
  for (int k = 0; k < T; ++k) {
    const int trow = ty * 8 + k;
    const float tinv = s_tinv[trow];

    float v0 = acc[k][0], v1 = acc[k][1], v2 = acc[k][2], v3 = acc[k][3];
    const int e0 = tx * 4, e1 = tx * 4 + 1, e2 = tx * 4 + 2, e3 = tx * 4 + 3;

    float cv[7];
    int ci[7];
#pragma unroll
    for (int r = 0; r < 7; ++r) {
      // in-lane top-1 (strict > keeps lowest index on ties)
      float rv = v0; int ri = e0;
      if (v1 > rv) { rv = v1; ri = e1; }
      if (v2 > rv) { rv = v2; ri = e2; }
      if (v3 > rv) { rv = v3; ri = e3; }
      // 16-lane butterfly (xor 1,2,4,8 stays within the 16-group)
#pragma unroll
      for (int m = 8; m >= 1; m >>= 1) {
        const float ov = __shfl_xor(rv, m);
        const int oi = __shfl_xor(ri, m);
        if (ov > rv || (ov == rv && oi < ri)) { rv = ov; ri = oi; }
      }
      cv[r] = rv; ci[r] = ri;
      // mask winner
      if (ri == e0) v0 = -INFINITY;
      if (ri == e1) v1 = -INFINITY;
      if (ri == e2) v2 = -INFINITY;
      if (ri == e3) v3 = -INFINITY;
    }

    // reversed order l <-> rank 6-l ; total = cos + bonus
    float tot[7];
    int gi[7];
#pragma unroll
    for (int l = 0; l < 7; ++l) {
      const int ce = ci[6 - l];
      tot[l] = cv[6 - l] * tinv * s_einv[ce] + s_bonus[ce];
      gi[l] = ce;
    }

    // top-2 of tot (stable)
    float bv = tot[0]; int bl = 0; int bgi = gi[0];
#pragma unroll
    for (int l = 1; l < 7; ++l)
      if (tot[l] > bv) { bv = tot[l]; bl = l; bgi = gi[l]; }
    float sv = -INFINITY; int sgi = 0;
#pragma unroll
    for (int l = 0; l < 7; ++l) {
      if (l == bl) continue;
      if (tot[l] > sv) { sv = tot[l]; sgi = gi[l]; }
    }

    const float ex1 = expf(sv - bv);
    const float z = 1.0f + ex1;
    if (tx == 0) {
      const int token = bt + trow;
      out_idx[2 * token]     = (float)sgi;
      out_idx[2 * token + 1] = (float)bgi;
      out_w[2 * token]     = ex1 / z;
      out_w[2 * token + 1] = 1.0f / z;
    }
  }
}

extern "C" void kernel_launch(void* const* d_in, const int* in_sizes, int n_in,
                              void* d_out, int out_size, void* d_ws, size_t ws_size,
                              hipStream_t stream) {
  const float* tokp  = (const float*)d_in[0];
  const float* expw  = (const float*)d_in[1];
  const float* cache = (const float*)d_in[2];
  float* out = (float*)d_out;
  float* einv = (float*)d_ws;

  const int n_tok = in_sizes[0] / D;       // 32768
  const int n_out_idx = n_tok * 2;         // 65536

  expert_norm_kernel<<<E, 256, 0, stream>>>(expw, einv);
  gate_kernel<<<n_tok / TOK, 256, 0, stream>>>(tokp, expw, cache, einv,
                                               out, out + n_out_idx);
}

// Round 4
// 126.447 us; speedup vs baseline: 2.6463x; 1.1522x over previous
//
#include <hip/hip_runtime.h>
#include <math.h>

#define EPSV 1e-8f

constexpr int D   = 1024;
constexpr int E   = 64;

// ---- split-K partial GEMM config ----
constexpr int SPLITK = 4;
constexpr int KS   = D / SPLITK;   // 256
constexpr int TOK  = 128;          // tokens per block
constexpr int DC   = 32;           // d-chunk (floats)
constexpr int NCHS = KS / DC;      // 8 chunks per slice
constexpr int NS   = DC / 4;       // 8 float4 slots per row
constexpr int T    = 8;            // tokens per thread
constexpr int EX   = 4;            // experts per thread

// ---------- prep: expert inverse norms ----------
__global__ __launch_bounds__(256) void expert_norm_kernel(const float* __restrict__ expw,
                                                          float* __restrict__ einv) {
  const int b = blockIdx.x;
  const int tid = threadIdx.x;
  const float4 v = *reinterpret_cast<const float4*>(expw + (size_t)b * D + tid * 4);
  float ss = v.x * v.x + v.y * v.y + v.z * v.z + v.w * v.w;
#pragma unroll
  for (int m = 32; m >= 1; m >>= 1) ss += __shfl_xor(ss, m);
  __shared__ float red[4];
  if ((tid & 63) == 0) red[tid >> 6] = ss;
  __syncthreads();
  if (tid == 0) {
    float t = (red[0] + red[1]) + (red[2] + red[3]);
    einv[b] = 1.0f / (sqrtf(t) + EPSV);
  }
}

// ---------- split-K partial sims ----------
__global__ __launch_bounds__(256) void partial_kernel(const float* __restrict__ tok,
                                                      const float* __restrict__ expw,
                                                      float* __restrict__ ws_sim,
                                                      float* __restrict__ ws_sq,
                                                      const int n_tok) {
  __shared__ float4 s_tok4[TOK * NS];
  __shared__ float4 s_exp4[E * NS];
  __shared__ float  s_part[TOK][NS];

  const int tid = threadIdx.x;
  const int ty = tid >> 4, tx = tid & 15;     // compute grid 16x16
  const int srow = tid >> 3, sslot = tid & 7; // staging grid 32x8
  const int bid = blockIdx.x;
  const int slice = bid & (SPLITK - 1);
  const int bt = (bid >> 2) * TOK;
  const int k0 = slice * KS;

  float acc[T][EX];
#pragma unroll
  for (int k = 0; k < T; ++k)
#pragma unroll
    for (int j = 0; j < EX; ++j) acc[k][j] = 0.f;
  float sqp[4] = {0.f, 0.f, 0.f, 0.f};

  const float* tp = tok + (size_t)(bt + srow) * D + k0 + sslot * 4;
  const float* ep = expw + (size_t)srow * D + k0 + sslot * 4;

  float4 tg[4], eg[2];
#pragma unroll
  for (int g = 0; g < 4; ++g) tg[g] = *reinterpret_cast<const float4*>(tp + (size_t)32 * g * D);
#pragma unroll
  for (int h = 0; h < 2; ++h) eg[h] = *reinterpret_cast<const float4*>(ep + (size_t)32 * h * D);

#pragma unroll 1
  for (int c = 0; c < NCHS; ++c) {
    __syncthreads();
#pragma unroll
    for (int g = 0; g < 4; ++g) {
      const int row = srow + 32 * g;
      s_tok4[row * NS + (sslot ^ ((row >> 3) & 7))] = tg[g];
      sqp[g] += tg[g].x * tg[g].x + tg[g].y * tg[g].y + tg[g].z * tg[g].z + tg[g].w * tg[g].w;
    }
#pragma unroll
    for (int h = 0; h < 2; ++h) {
      const int row = srow + 32 * h;
      s_exp4[row * NS + (sslot ^ ((row >> 2) & 7))] = eg[h];
    }
    __syncthreads();
    if (c + 1 < NCHS) {
      const int off = (c + 1) * DC;
#pragma unroll
      for (int g = 0; g < 4; ++g)
        tg[g] = *reinterpret_cast<const float4*>(tp + (size_t)32 * g * D + off);
#pragma unroll
      for (int h = 0; h < 2; ++h)
        eg[h] = *reinterpret_cast<const float4*>(ep + (size_t)32 * h * D + off);
    }
#pragma unroll
    for (int d4 = 0; d4 < NS; ++d4) {
      float4 ef[EX];
#pragma unroll
      for (int j = 0; j < EX; ++j)
        ef[j] = s_exp4[(tx * 4 + j) * NS + (d4 ^ (tx & 7))];
#pragma unroll
      for (int k = 0; k < T; ++k) {
        const float4 tv = s_tok4[(ty * 8 + k) * NS + (d4 ^ (ty & 7))];
#pragma unroll
        for (int j = 0; j < EX; ++j) {
          acc[k][j] = fmaf(tv.x, ef[j].x, acc[k][j]);
          acc[k][j] = fmaf(tv.y, ef[j].y, acc[k][j]);
          acc[k][j] = fmaf(tv.z, ef[j].z, acc[k][j]);
          acc[k][j] = fmaf(tv.w, ef[j].w, acc[k][j]);
        }
      }
    }
  }

  // write partial sims
#pragma unroll
  for (int k = 0; k < T; ++k) {
    const int row = ty * 8 + k;
    const float4 v = make_float4(acc[k][0], acc[k][1], acc[k][2], acc[k][3]);
    reinterpret_cast<float4*>(ws_sim)[((size_t)slice * n_tok + bt + row) * (E / 4) + tx] = v;
  }
  // partial token sumsq
#pragma unroll
  for (int g = 0; g < 4; ++g) s_part[srow + 32 * g][sslot] = sqp[g];
  __syncthreads();
  if (tid < TOK) {
    float ss = 0.f;
#pragma unroll
    for (int p = 0; p < NS; ++p) ss += s_part[tid][p];
    ws_sq[(size_t)slice * n_tok + bt + tid] = ss;
  }
}

// ---------- reduce + selection (lane == expert, 64-lane butterfly) ----------
__global__ __launch_bounds__(256) void select_kernel(const float* __restrict__ ws_sim,
                                                     const float* __restrict__ ws_sq,
                                                     const float* __restrict__ einv_g,
                                                     const float* __restrict__ cache,
                                                     const int n_tok,
                                                     float* __restrict__ out_idx,
                                                     float* __restrict__ out_w) {
  const int tid = threadIdx.x;
  const int lane = tid & 63;
  const int w = tid >> 6;
  const float einv = einv_g[lane];
  const float bonus = 0.1f * cache[lane];
  const int t0 = blockIdx.x * 32 + w * 8;

  float sims[8], sss[8];
#pragma unroll
  for (int i = 0; i < 8; ++i) {
    const int t = t0 + i;
    const float s0 = ws_sim[((size_t)0 * n_tok + t) * E + lane];
    const float s1 = ws_sim[((size_t)1 * n_tok + t) * E + lane];
    const float s2 = ws_sim[((size_t)2 * n_tok + t) * E + lane];
    const float s3 = ws_sim[((size_t)3 * n_tok + t) * E + lane];
    sims[i] = (s0 + s1) + (s2 + s3);
    const float q0 = ws_sq[(size_t)0 * n_tok + t];
    const float q1 = ws_sq[(size_t)1 * n_tok + t];
    const float q2 = ws_sq[(size_t)2 * n_tok + t];
    const float q3 = ws_sq[(size_t)3 * n_tok + t];
    sss[i] = (q0 + q1) + (q2 + q3);
  }

#pragma unroll 1
  for (int i = 0; i < 8; ++i) {
    const int token = t0 + i;
    const float tinv = 1.0f / (sqrtf(sss[i]) + EPSV);

    // top-7 by sim, descending, ties -> lowest expert index
    float v = sims[i];
    int vi = lane;
    float cv[7];
    int ci[7];
#pragma unroll
    for (int r = 0; r < 7; ++r) {
      float rv = v;
      int ri = vi;
#pragma unroll
      for (int m = 32; m >= 1; m >>= 1) {
        const float ov = __shfl_xor(rv, m);
        const int oi = __shfl_xor(ri, m);
        if (ov > rv || (ov == rv && oi < ri)) { rv = ov; ri = oi; }
      }
      cv[r] = rv; ci[r] = ri;
      if (vi == ri) v = -INFINITY;
    }

    // reversed order l <-> rank 6-l ; total = cos + bonus
    float tot[7];
    int gi[7];
#pragma unroll
    for (int l = 0; l < 7; ++l) {
      const int ce = ci[6 - l];
      const float ei = __shfl(einv, ce);
      const float bo = __shfl(bonus, ce);
      tot[l] = cv[6 - l] * tinv * ei + bo;
      gi[l] = ce;
    }

    // top-2 of tot (stable)
    float bv = tot[0]; int bl = 0; int bgi = gi[0];
#pragma unroll
    for (int l = 1; l < 7; ++l)
      if (tot[l] > bv) { bv = tot[l]; bl = l; bgi = gi[l]; }
    float sv = -INFINITY; int sgi = 0;
#pragma unroll
    for (int l = 0; l < 7; ++l) {
      if (l == bl) continue;
      if (tot[l] > sv) { sv = tot[l]; sgi = gi[l]; }
    }

    const float ex1 = expf(sv - bv);
    const float z = 1.0f + ex1;
    if (lane == 0) {
      out_idx[2 * token]     = (float)sgi;
      out_idx[2 * token + 1] = (float)bgi;
      out_w[2 * token]     = ex1 / z;
      out_w[2 * token + 1] = 1.0f / z;
    }
  }
}

// ---------- fallback: round-3 monolithic kernel (used if ws too small) ----------
constexpr int FTOK = 128;
constexpr int FNS  = 16;

__global__ __launch_bounds__(256) void gate_full_kernel(const float* __restrict__ tok,
                                                        const float* __restrict__ expw,
                                                        const float* __restrict__ cache,
                                                        const float* __restrict__ einv_g,
                                                        float* __restrict__ out_idx,
                                                        float* __restrict__ out_w) {
  __shared__ float4 s_tok4[FTOK * FNS];
  __shared__ float4 s_exp4[E * FNS];
  __shared__ float  s_part[FTOK][FNS];
  __shared__ float  s_tinv[FTOK];
  __shared__ float  s_einv[E];
  __shared__ float  s_bonus[E];

  const int tid = threadIdx.x;
  const int ty = tid >> 4, tx = tid & 15;
  const int srow = tid >> 4, sslot = tid & 15;
  const int bt = blockIdx.x * FTOK;

  if (tid < E) { s_einv[tid] = einv_g[tid]; s_bonus[tid] = 0.1f * cache[tid]; }

  float acc[8][4];
#pragma unroll
  for (int k = 0; k < 8; ++k)
#pragma unroll
    for (int j = 0; j < 4; ++j) acc[k][j] = 0.f;
  float sqp[8];
#pragma unroll
  for (int g = 0; g < 8; ++g) sqp[g] = 0.f;

  float4 tg[8], eg[4];
#pragma unroll
  for (int g = 0; g < 8; ++g)
    tg[g] = *reinterpret_cast<const float4*>(tok + (size_t)(bt + srow + 16 * g) * D + sslot * 4);
#pragma unroll
  for (int h = 0; h < 4; ++h)
    eg[h] = *reinterpret_cast<const float4*>(expw + (size_t)(srow + 16 * h) * D + sslot * 4);

#pragma unroll 1
  for (int c = 0; c < 16; ++c) {
    __syncthreads();
#pragma unroll
    for (int g = 0; g < 8; ++g) {
      const int row = srow + 16 * g;
      s_tok4[row * FNS + (sslot ^ ((row >> 3) & 7))] = tg[g];
      sqp[g] += tg[g].x * tg[g].x + tg[g].y * tg[g].y + tg[g].z * tg[g].z + tg[g].w * tg[g].w;
    }
#pragma unroll
    for (int h = 0; h < 4; ++h) {
      const int row = srow + 16 * h;
      s_exp4[row * FNS + (sslot ^ ((row >> 2) & 7))] = eg[h];
    }
    __syncthreads();
    if (c + 1 < 16) {
      const int off = (c + 1) * 64 + sslot * 4;
#pragma unroll
      for (int g = 0; g < 8; ++g)
        tg[g] = *reinterpret_cast<const float4*>(tok + (size_t)(bt + srow + 16 * g) * D + off);
#pragma unroll
      for (int h = 0; h < 4; ++h)
        eg[h] = *reinterpret_cast<const float4*>(expw + (size_t)(srow + 16 * h) * D + off);
    }
#pragma unroll
    for (int d4 = 0; d4 < FNS; ++d4) {
      float4 ef[4];
#pragma unroll
      for (int j = 0; j < 4; ++j)
        ef[j] = s_exp4[(tx * 4 + j) * FNS + (d4 ^ (tx & 7))];
#pragma unroll
      for (int k = 0; k < 8; ++k) {
        const float4 tv = s_tok4[(ty * 8 + k) * FNS + (d4 ^ (ty & 7))];
#pragma unroll
        for (int j = 0; j < 4; ++j) {
          acc[k][j] = fmaf(tv.x, ef[j].x, acc[k][j]);
          acc[k][j] = fmaf(tv.y, ef[j].y, acc[k][j]);
          acc[k][j] = fmaf(tv.z, ef[j].z, acc[k][j]);
          acc[k][j] = fmaf(tv.w, ef[j].w, acc[k][j]);
        }
      }
    }
  }

#pragma unroll
  for (int g = 0; g < 8; ++g) s_part[srow + 16 * g][sslot] = sqp[g];
  __syncthreads();
  if (tid < FTOK) {
    float ss = 0.f;
#pragma unroll
    for (int p = 0; p < FNS; ++p) ss += s_part[tid][p];
    s_tinv[tid] = 1.0f / (sqrtf(ss) + EPSV);
  }
  __syncthreads();

#pragma unroll 1
  for (int k = 0; k < 8; ++k) {
    const int trow = ty * 8 + k;
    const float tinv = s_tinv[trow];
    float v0 = acc[k][0], v1 = acc[k][1], v2 = acc[k][2], v3 = acc[k][3];
    const int e0 = tx * 4, e1 = tx * 4 + 1, e2 = tx * 4 + 2, e3 = tx * 4 + 3;
    float cv[7]; int ci[7];
#pragma unroll
    for (int r = 0; r < 7; ++r) {
      float rv = v0; int ri = e0;
      if (v1 > rv) { rv = v1; ri = e1; }
      if (v2 > rv) { rv = v2; ri = e2; }
      if (v3 > rv) { rv = v3; ri = e3; }
#pragma unroll
      for (int m = 8; m >= 1; m >>= 1) {
        const float ov = __shfl_xor(rv, m);
        const int oi = __shfl_xor(ri, m);
        if (ov > rv || (ov == rv && oi < ri)) { rv = ov; ri = oi; }
      }
      cv[r] = rv; ci[r] = ri;
      if (ri == e0) v0 = -INFINITY;
      if (ri == e1) v1 = -INFINITY;
      if (ri == e2) v2 = -INFINITY;
      if (ri == e3) v3 = -INFINITY;
    }
    float tot[7]; int gi[7];
#pragma unroll
    for (int l = 0; l < 7; ++l) {
      const int ce = ci[6 - l];
      tot[l] = cv[6 - l] * tinv * s_einv[ce] + s_bonus[ce];
      gi[l] = ce;
    }
    float bv = tot[0]; int bl = 0; int bgi = gi[0];
#pragma unroll
    for (int l = 1; l < 7; ++l)
      if (tot[l] > bv) { bv = tot[l]; bl = l; bgi = gi[l]; }
    float sv = -INFINITY; int sgi = 0;
#pragma unroll
    for (int l = 0; l < 7; ++l) {
      if (l == bl) continue;
      if (tot[l] > sv) { sv = tot[l]; sgi = gi[l]; }
    }
    const float ex1 = expf(sv - bv);
    const float z = 1.0f + ex1;
    if (tx == 0) {
      const int token = bt + trow;
      out_idx[2 * token]     = (float)sgi;
      out_idx[2 * token + 1] = (float)bgi;
      out_w[2 * token]     = ex1 / z;
      out_w[2 * token + 1] = 1.0f / z;
    }
  }
}

extern "C" void kernel_launch(void* const* d_in, const int* in_sizes, int n_in,
                              void* d_out, int out_size, void* d_ws, size_t ws_size,
                              hipStream_t stream) {
  const float* tokp  = (const float*)d_in[0];
  const float* expw  = (const float*)d_in[1];
  const float* cache = (const float*)d_in[2];
  float* out = (float*)d_out;

  const int n_tok = in_sizes[0] / D;       // 32768
  const int n_out_idx = n_tok * 2;

  // workspace layout: [einv: 1KB][ws_sq: SPLITK*n_tok*4][ws_sim: SPLITK*n_tok*E*4]
  float* einv = (float*)d_ws;
  float* ws_sq = (float*)((char*)d_ws + 1024);
  float* ws_sim = ws_sq + (size_t)SPLITK * n_tok;
  const size_t need = 1024 + (size_t)SPLITK * n_tok * 4 + (size_t)SPLITK * n_tok * E * 4;

  expert_norm_kernel<<<E, 256, 0, stream>>>(expw, einv);
  if (ws_size >= need) {
    partial_kernel<<<(n_tok / TOK) * SPLITK, 256, 0, stream>>>(tokp, expw, ws_sim, ws_sq, n_tok);
    select_kernel<<<n_tok / 32, 256, 0, stream>>>(ws_sim, ws_sq, einv, cache, n_tok,
                                                  out, out + n_out_idx);
  } else {
    gate_full_kernel<<<n_tok / FTOK, 256, 0, stream>>>(tokp, expw, cache, einv,
                                                       out, out + n_out_idx);
  }
}